// Round 1
// baseline (249.282 us; speedup 1.0000x reference)
//
#include <hip/hip_runtime.h>
#include <math.h>

#define NPTS 6890
#define BATCH 1024
#define FLOATS_PER_BATCH (NPTS * 3)   // 20670; mod 4 == 2
#define NGROUPS 1722                  // groups of 4 points covered by float4s
#define CHUNKS 2                      // reduce blocks per batch

// Accumulate one point-pair into the 16 sums.
__device__ __forceinline__ void accum(float* acc, float p0, float p1, float p2,
                                      float g0, float g1, float g2) {
  acc[0] += p0;  acc[1] += p1;  acc[2] += p2;
  acc[3] += g0;  acc[4] += g1;  acc[5] += g2;
  acc[6] += p0 * p0 + p1 * p1 + p2 * p2;
  acc[7]  += p0 * g0;  acc[8]  += p0 * g1;  acc[9]  += p0 * g2;
  acc[10] += p1 * g0;  acc[11] += p1 * g1;  acc[12] += p1 * g2;
  acc[13] += p2 * g0;  acc[14] += p2 * g1;  acc[15] += p2 * g2;
}

// Accumulate 4 points given the 3 pred float4s and 3 gt float4s of a group.
__device__ __forceinline__ void accum_group(float* acc,
                                            const float4& a0, const float4& a1,
                                            const float4& a2, const float4& e0,
                                            const float4& e1, const float4& e2) {
  accum(acc, a0.x, a0.y, a0.z, e0.x, e0.y, e0.z);
  accum(acc, a0.w, a1.x, a1.y, e0.w, e1.x, e1.y);
  accum(acc, a1.z, a1.w, a2.x, e1.z, e1.w, e2.x);
  accum(acc, a2.y, a2.z, a2.w, e2.y, e2.z, e2.w);
}

// ---------------------------------------------------------------------------
// Kernel 1: per-(batch,chunk) reduction of 16 raw sums.
//   [0..2] sum p  [3..5] sum g  [6] sum|p|^2  [7..15] sum p_i*g_j
// grid = (BATCH, CHUNKS). Chunk c of batch b covers groups:
//   pair A: {c*256+t, c*256+t+512}        (always valid, t in [0,256))
//   pair B: {c*256+t+1024}                (always valid)
//           {t+1536}                      (c==0 only, valid iff t<186)
// 12 float4 loads are issued per pair before any FMA -> deep MLP.
// Batch base b*20670 is 16B-aligned only for even b; odd b skips 2 points
// (6 floats) to realign. The 2 leftover points are handled scalar in c==0.
// ---------------------------------------------------------------------------
__global__ __launch_bounds__(256, 4) void reduce_kernel(
    const float* __restrict__ pred, const float* __restrict__ gt,
    float* __restrict__ partial) {
  const int b = blockIdx.x;
  const int c = blockIdx.y;
  const size_t ofs0 = (size_t)b * FLOATS_PER_BATCH;
  const int skip = (b & 1) ? 2 : 0;                  // points skipped at head
  const size_t ofs = ofs0 + (size_t)skip * 3;        // 16B-aligned float idx
  const float4* __restrict__ P = (const float4*)(pred + ofs);
  const float4* __restrict__ G = (const float4*)(gt + ofs);

  float acc[16];
#pragma unroll
  for (int i = 0; i < 16; ++i) acc[i] = 0.f;

  const int t = (int)threadIdx.x;
  const int g1 = c * 256 + t;          // [0,512)
  const int g2 = g1 + 512;             // [512,1024)

  {  // pair A: both groups always valid; 12 loads in flight
    const float4 a0 = P[3 * g1], a1 = P[3 * g1 + 1], a2 = P[3 * g1 + 2];
    const float4 b0 = P[3 * g2], b1 = P[3 * g2 + 1], b2 = P[3 * g2 + 2];
    const float4 e0 = G[3 * g1], e1 = G[3 * g1 + 1], e2 = G[3 * g1 + 2];
    const float4 f0 = G[3 * g2], f1 = G[3 * g2 + 1], f2 = G[3 * g2 + 2];
    accum_group(acc, a0, a1, a2, e0, e1, e2);
    accum_group(acc, b0, b1, b2, f0, f1, f2);
  }

  const int g3 = g1 + 1024;            // [1024,1536) -> always < NGROUPS
  if (c == 0) {                        // block-uniform branch
    const int g4 = t + 1536;           // valid iff t < 186
    const bool v4 = g4 < NGROUPS;
    const int g4c = v4 ? g4 : g3;      // clamp keeps the load in-bounds
    const float4 a0 = P[3 * g3], a1 = P[3 * g3 + 1], a2 = P[3 * g3 + 2];
    const float4 b0 = P[3 * g4c], b1 = P[3 * g4c + 1], b2 = P[3 * g4c + 2];
    const float4 e0 = G[3 * g3], e1 = G[3 * g3 + 1], e2 = G[3 * g3 + 2];
    const float4 f0 = G[3 * g4c], f1 = G[3 * g4c + 1], f2 = G[3 * g4c + 2];
    accum_group(acc, a0, a1, a2, e0, e1, e2);
    if (v4) accum_group(acc, b0, b1, b2, f0, f1, f2);
  } else {
    const float4 a0 = P[3 * g3], a1 = P[3 * g3 + 1], a2 = P[3 * g3 + 2];
    const float4 e0 = G[3 * g3], e1 = G[3 * g3 + 1], e2 = G[3 * g3 + 2];
    accum_group(acc, a0, a1, a2, e0, e1, e2);
  }

  // 2 leftover scalar points per batch (chunk 0 only)
  if (c == 0 && t < 2) {
    const int n = skip ? t : (NPTS - 2 + t);
    const float* pp = pred + ofs0 + 3 * n;
    const float* gg = gt + ofs0 + 3 * n;
    accum(acc, pp[0], pp[1], pp[2], gg[0], gg[1], gg[2]);
  }

  // Cheap tail: 2 shfl_xor stages (sum across the 4 groups-of-16 lanes),
  // then LDS cross-lane/wave sum. Replaces the 96-shuffle full butterfly.
#pragma unroll
  for (int i = 0; i < 16; ++i) {
    acc[i] += __shfl_xor(acc[i], 16, 64);
    acc[i] += __shfl_xor(acc[i], 32, 64);
  }
  // lanes 0..15 of each wave now hold the residue-class partials
  __shared__ float red[4][16][17];     // +1 pad to dodge bank conflicts
  const int wave = t >> 6;
  const int lane = t & 63;
  if (lane < 16) {
#pragma unroll
    for (int i = 0; i < 16; ++i) red[wave][lane][i] = acc[i];
  }
  __syncthreads();
  if (t < 16) {
    float s = 0.f;
#pragma unroll
    for (int w = 0; w < 4; ++w)
#pragma unroll
      for (int r = 0; r < 16; ++r) s += red[w][r][t];
    partial[(b * CHUNKS + c) * 16 + t] = s;
  }
}

// ---------------------------------------------------------------------------
// Kernel 2: per-batch solve (fp64). One thread per batch; 64-thread blocks
// spread the fp64 Jacobi work over 16 CUs instead of 4. Sums CHUNKS partials.
// ---------------------------------------------------------------------------
__global__ void solve_kernel(const float* __restrict__ partial,
                             float* __restrict__ params) {
  const int b = blockIdx.x * blockDim.x + threadIdx.x;
  if (b >= BATCH) return;
  const float* ps = partial + b * (CHUNKS * 16);
  double s[16];
#pragma unroll
  for (int i = 0; i < 16; ++i)
    s[i] = (double)ps[i] + (double)ps[16 + i];

  const double Ninv = 1.0 / (double)NPTS;

  double sp[3] = {s[0], s[1], s[2]};
  double sg[3] = {s[3], s[4], s[5]};
  double mu1[3], mu2[3];
#pragma unroll
  for (int i = 0; i < 3; ++i) { mu1[i] = sp[i] * Ninv; mu2[i] = sg[i] * Ninv; }
  const double var1 =
      s[6] - (sp[0] * sp[0] + sp[1] * sp[1] + sp[2] * sp[2]) * Ninv;

  double K[3][3];
#pragma unroll
  for (int i = 0; i < 3; ++i)
#pragma unroll
    for (int j = 0; j < 3; ++j)
      K[i][j] = s[7 + 3 * i + j] - sp[i] * sg[j] * Ninv + 1e-8;

  double A[3][3];
#pragma unroll
  for (int i = 0; i < 3; ++i)
#pragma unroll
    for (int j = 0; j < 3; ++j)
      A[i][j] = K[0][i] * K[0][j] + K[1][i] * K[1][j] + K[2][i] * K[2][j];

  double V[3][3] = {{1, 0, 0}, {0, 1, 0}, {0, 0, 1}};
  for (int sweep = 0; sweep < 30; ++sweep) {
    const double off = A[0][1] * A[0][1] + A[0][2] * A[0][2] + A[1][2] * A[1][2];
    const double nrm = A[0][0] + A[1][1] + A[2][2];
    if (off <= 1e-30 * nrm * nrm) break;
    for (int pq = 0; pq < 3; ++pq) {
      const int p = (pq == 2) ? 1 : 0;
      const int q = (pq == 0) ? 1 : 2;
      const double apq = A[p][q];
      if (apq == 0.0) continue;
      const double theta = (A[q][q] - A[p][p]) / (2.0 * apq);
      const double tt =
          ((theta >= 0.0) ? 1.0 : -1.0) / (fabs(theta) + sqrt(theta * theta + 1.0));
      const double cc = 1.0 / sqrt(tt * tt + 1.0);
      const double sn = tt * cc;
      const double app = A[p][p], aqq = A[q][q];
      A[p][p] = app - tt * apq;
      A[q][q] = aqq + tt * apq;
      A[p][q] = 0.0; A[q][p] = 0.0;
      const int r = 3 - p - q;
      const double arp = A[r][p], arq = A[r][q];
      A[r][p] = cc * arp - sn * arq; A[p][r] = A[r][p];
      A[r][q] = sn * arp + cc * arq; A[q][r] = A[r][q];
#pragma unroll
      for (int k = 0; k < 3; ++k) {
        const double vkp = V[k][p], vkq = V[k][q];
        V[k][p] = cc * vkp - sn * vkq;
        V[k][q] = sn * vkp + cc * vkq;
      }
    }
  }

  double w[3] = {A[0][0], A[1][1], A[2][2]};
  int i0 = 0, i1 = 1, i2 = 2, tmp;
  if (w[i0] < w[i1]) { tmp = i0; i0 = i1; i1 = tmp; }
  if (w[i0] < w[i2]) { tmp = i0; i0 = i2; i2 = tmp; }
  if (w[i1] < w[i2]) { tmp = i1; i1 = i2; i2 = tmp; }
  const double sv0 = sqrt(fmax(w[i0], 0.0));
  const double sv1 = sqrt(fmax(w[i1], 0.0));
  const double sv2 = sqrt(fmax(w[i2], 0.0));

  const double detK =
      K[0][0] * (K[1][1] * K[2][2] - K[1][2] * K[2][1]) -
      K[0][1] * (K[1][0] * K[2][2] - K[1][2] * K[2][0]) +
      K[0][2] * (K[1][0] * K[2][1] - K[1][1] * K[2][0]);
  const double sgn = (detK > 0.0) ? 1.0 : ((detK < 0.0) ? -1.0 : 0.0);

  const double floor0 = sv0 * 1e-12 + 1e-300;
  const double z0 = 1.0 / fmax(sv0, floor0);
  const double z1 = 1.0 / fmax(sv1, floor0);
  const double z2 = sgn / fmax(sv2, floor0);

  double W[3][3];
#pragma unroll
  for (int a = 0; a < 3; ++a)
#pragma unroll
    for (int c = 0; c < 3; ++c)
      W[a][c] = V[a][i0] * V[c][i0] * z0 + V[a][i1] * V[c][i1] * z1 +
                V[a][i2] * V[c][i2] * z2;

  double R[3][3];
#pragma unroll
  for (int a = 0; a < 3; ++a)
#pragma unroll
    for (int c = 0; c < 3; ++c)
      R[a][c] = W[a][0] * K[c][0] + W[a][1] * K[c][1] + W[a][2] * K[c][2];

  const double trace = sv0 + sv1 + sgn * sv2;
  const double scale = trace / var1;

  float* pr = params + b * 12;
#pragma unroll
  for (int a = 0; a < 3; ++a) {
#pragma unroll
    for (int c = 0; c < 3; ++c) pr[3 * a + c] = (float)(scale * R[a][c]);
    pr[9 + a] = (float)(mu2[a] - scale * (R[a][0] * mu1[0] + R[a][1] * mu1[1] +
                                          R[a][2] * mu1[2]));
  }
}

// ---------------------------------------------------------------------------
// Kernel 3: apply |M p + t - g| per point, float4-vectorized (4 pts/thread).
// (unchanged this round — isolating the reduce/solve changes)
// ---------------------------------------------------------------------------
__device__ __forceinline__ void xform(const float* m, float p0, float p1,
                                      float p2, float g0, float g1, float g2,
                                      float& o0, float& o1, float& o2) {
  o0 = fabsf(m[0] * p0 + m[1] * p1 + m[2] * p2 + m[9] - g0);
  o1 = fabsf(m[3] * p0 + m[4] * p1 + m[5] * p2 + m[10] - g1);
  o2 = fabsf(m[6] * p0 + m[7] * p1 + m[8] * p2 + m[11] - g2);
}

__global__ __launch_bounds__(256) void apply_kernel(
    const float* __restrict__ pred, const float* __restrict__ gt,
    const float* __restrict__ params, float* __restrict__ out) {
  const int b = blockIdx.y;
  float m[12];
#pragma unroll
  for (int i = 0; i < 12; ++i) m[i] = params[b * 12 + i];  // uniform -> s_load

  const size_t ofs0 = (size_t)b * FLOATS_PER_BATCH;
  const int skip = (b & 1) ? 2 : 0;
  const size_t ofs = ofs0 + (size_t)skip * 3;
  const int gi = blockIdx.x * 256 + threadIdx.x;

  if (gi < NGROUPS) {
    const float4* __restrict__ p4 = (const float4*)(pred + ofs);
    const float4* __restrict__ g4 = (const float4*)(gt + ofs);
    float4* __restrict__ o4 = (float4*)(out + ofs);
    const float4 a0 = p4[3 * gi], a1 = p4[3 * gi + 1], a2 = p4[3 * gi + 2];
    const float4 c0 = g4[3 * gi], c1 = g4[3 * gi + 1], c2 = g4[3 * gi + 2];
    float4 r0, r1, r2;
    xform(m, a0.x, a0.y, a0.z, c0.x, c0.y, c0.z, r0.x, r0.y, r0.z);
    xform(m, a0.w, a1.x, a1.y, c0.w, c1.x, c1.y, r0.w, r1.x, r1.y);
    xform(m, a1.z, a1.w, a2.x, c1.z, c1.w, c2.x, r1.z, r1.w, r2.x);
    xform(m, a2.y, a2.z, a2.w, c2.y, c2.z, c2.w, r2.y, r2.z, r2.w);
    o4[3 * gi] = r0; o4[3 * gi + 1] = r1; o4[3 * gi + 2] = r2;
  }

  // 2 leftover scalar points per batch
  if (blockIdx.x == 0 && threadIdx.x < 2) {
    const int n = skip ? (int)threadIdx.x : (NPTS - 2 + (int)threadIdx.x);
    const float* pp = pred + ofs0 + 3 * n;
    const float* gg = gt + ofs0 + 3 * n;
    float* oo = out + ofs0 + 3 * n;
    xform(m, pp[0], pp[1], pp[2], gg[0], gg[1], gg[2], oo[0], oo[1], oo[2]);
  }
}

extern "C" void kernel_launch(void* const* d_in, const int* in_sizes, int n_in,
                              void* d_out, int out_size, void* d_ws, size_t ws_size,
                              hipStream_t stream) {
  const float* pred = (const float*)d_in[0];
  const float* gt   = (const float*)d_in[1];
  float* out = (float*)d_out;
  float* partial = (float*)d_ws;                    // BATCH*CHUNKS*16 floats
  float* params  = partial + BATCH * CHUNKS * 16;   // BATCH*12 floats

  hipLaunchKernelGGL(reduce_kernel, dim3(BATCH, CHUNKS), dim3(256), 0, stream,
                     pred, gt, partial);
  hipLaunchKernelGGL(solve_kernel, dim3((BATCH + 63) / 64), dim3(64), 0,
                     stream, partial, params);
  hipLaunchKernelGGL(apply_kernel, dim3((NGROUPS + 255) / 256, BATCH),
                     dim3(256), 0, stream, pred, gt, params, out);
}

// Round 2
// 247.525 us; speedup vs baseline: 1.0071x; 1.0071x over previous
//
#include <hip/hip_runtime.h>
#include <math.h>

#define NPTS 6890
#define BATCH 1024
#define FLOATS_PER_BATCH (NPTS * 3)   // 20670; mod 4 == 2
#define NGROUPS 1722                  // groups of 4 points covered by float4s
#define TOTAL_F4 (NGROUPS * 3)        // 5166 float4s in the aligned region
#define TILE_F4 768                   // float4s staged per tile (=256 groups)
#define NTILES 7                      // 6 full tiles + 1 partial (558 f4)
#define CHUNKS 2                      // reduce blocks per batch

// Accumulate one point-pair into the 16 sums.
__device__ __forceinline__ void accum(float* acc, float p0, float p1, float p2,
                                      float g0, float g1, float g2) {
  acc[0] += p0;  acc[1] += p1;  acc[2] += p2;
  acc[3] += g0;  acc[4] += g1;  acc[5] += g2;
  acc[6] += p0 * p0 + p1 * p1 + p2 * p2;
  acc[7]  += p0 * g0;  acc[8]  += p0 * g1;  acc[9]  += p0 * g2;
  acc[10] += p1 * g0;  acc[11] += p1 * g1;  acc[12] += p1 * g2;
  acc[13] += p2 * g0;  acc[14] += p2 * g1;  acc[15] += p2 * g2;
}

// Accumulate 4 points given the 3 pred float4s and 3 gt float4s of a group.
__device__ __forceinline__ void accum_group(float* acc,
                                            const float4& a0, const float4& a1,
                                            const float4& a2, const float4& e0,
                                            const float4& e1, const float4& e2) {
  accum(acc, a0.x, a0.y, a0.z, e0.x, e0.y, e0.z);
  accum(acc, a0.w, a1.x, a1.y, e0.w, e1.x, e1.y);
  accum(acc, a1.z, a1.w, a2.x, e1.z, e1.w, e2.x);
  accum(acc, a2.y, a2.z, a2.w, e2.y, e2.z, e2.w);
}

// ---------------------------------------------------------------------------
// Kernel 1: per-(batch,chunk) reduction of 16 raw sums, LDS-staged.
//   [0..2] sum p  [3..5] sum g  [6] sum|p|^2  [7..15] sum p_i*g_j
// Global loads are fully coalesced (lane i <-> base+16i); the 48B-stride
// point gather happens in LDS, where ds_read_b128 at 48B stride is
// bank-bijective (conflict-free). Chunk 0 covers tiles 0..3, chunk 1 tiles
// 4..6 (tile 6 partial: 558 f4 = 186 groups).
// Batch base b*20670 is 16B-aligned only for even b; odd b skips 2 points
// (6 floats) to realign. The 2 leftover points are handled scalar in c==0.
// ---------------------------------------------------------------------------
__global__ __launch_bounds__(256, 4) void reduce_kernel(
    const float* __restrict__ pred, const float* __restrict__ gt,
    float* __restrict__ partial) {
  const int b = blockIdx.x;
  const int c = blockIdx.y;
  const size_t ofs0 = (size_t)b * FLOATS_PER_BATCH;
  const int skip = (b & 1) ? 2 : 0;                  // points skipped at head
  const size_t ofs = ofs0 + (size_t)skip * 3;        // 16B-aligned float idx
  const float4* __restrict__ P = (const float4*)(pred + ofs);
  const float4* __restrict__ G = (const float4*)(gt + ofs);

  __shared__ float4 LP[TILE_F4];
  __shared__ float4 LG[TILE_F4];
  __shared__ float red[4][16][17];     // +1 pad to dodge bank conflicts

  float acc[16];
#pragma unroll
  for (int i = 0; i < 16; ++i) acc[i] = 0.f;

  const int t = (int)threadIdx.x;
  const int tile_beg = (c == 0) ? 0 : 4;
  const int tile_end = (c == 0) ? 4 : NTILES;

  for (int tile = tile_beg; tile < tile_end; ++tile) {
    const int base = tile * TILE_F4;
    const int nf4 = (base + TILE_F4 <= TOTAL_F4) ? TILE_F4 : (TOTAL_F4 - base);
    // coalesced global -> LDS stage (6 wave-contiguous dwordx4 loads)
#pragma unroll
    for (int k = 0; k < 3; ++k) {
      const int idx = t + 256 * k;
      if (idx < nf4) {
        LP[idx] = P[base + idx];
        LG[idx] = G[base + idx];
      }
    }
    __syncthreads();
    const int ngr = nf4 / 3;           // 256 or 186 groups
    if (t < ngr) {
      const float4 a0 = LP[3 * t], a1 = LP[3 * t + 1], a2 = LP[3 * t + 2];
      const float4 e0 = LG[3 * t], e1 = LG[3 * t + 1], e2 = LG[3 * t + 2];
      accum_group(acc, a0, a1, a2, e0, e1, e2);
    }
    __syncthreads();
  }

  // 2 leftover scalar points per batch (chunk 0 only)
  if (c == 0 && t < 2) {
    const int n = skip ? t : (NPTS - 2 + t);
    const float* pp = pred + ofs0 + 3 * n;
    const float* gg = gt + ofs0 + 3 * n;
    accum(acc, pp[0], pp[1], pp[2], gg[0], gg[1], gg[2]);
  }

  // Cheap tail: 2 shfl_xor stages, then LDS cross-lane/wave sum.
#pragma unroll
  for (int i = 0; i < 16; ++i) {
    acc[i] += __shfl_xor(acc[i], 16, 64);
    acc[i] += __shfl_xor(acc[i], 32, 64);
  }
  const int wave = t >> 6;
  const int lane = t & 63;
  if (lane < 16) {
#pragma unroll
    for (int i = 0; i < 16; ++i) red[wave][lane][i] = acc[i];
  }
  __syncthreads();
  if (t < 16) {
    float s = 0.f;
#pragma unroll
    for (int w = 0; w < 4; ++w)
#pragma unroll
      for (int r = 0; r < 16; ++r) s += red[w][r][t];
    partial[(b * CHUNKS + c) * 16 + t] = s;
  }
}

// ---------------------------------------------------------------------------
// Kernel 2: per-batch solve (fp64). One thread per batch; 64-thread blocks
// spread the fp64 Jacobi work over 16 CUs. Sums CHUNKS partials. (unchanged)
// ---------------------------------------------------------------------------
__global__ void solve_kernel(const float* __restrict__ partial,
                             float* __restrict__ params) {
  const int b = blockIdx.x * blockDim.x + threadIdx.x;
  if (b >= BATCH) return;
  const float* ps = partial + b * (CHUNKS * 16);
  double s[16];
#pragma unroll
  for (int i = 0; i < 16; ++i)
    s[i] = (double)ps[i] + (double)ps[16 + i];

  const double Ninv = 1.0 / (double)NPTS;

  double sp[3] = {s[0], s[1], s[2]};
  double sg[3] = {s[3], s[4], s[5]};
  double mu1[3], mu2[3];
#pragma unroll
  for (int i = 0; i < 3; ++i) { mu1[i] = sp[i] * Ninv; mu2[i] = sg[i] * Ninv; }
  const double var1 =
      s[6] - (sp[0] * sp[0] + sp[1] * sp[1] + sp[2] * sp[2]) * Ninv;

  double K[3][3];
#pragma unroll
  for (int i = 0; i < 3; ++i)
#pragma unroll
    for (int j = 0; j < 3; ++j)
      K[i][j] = s[7 + 3 * i + j] - sp[i] * sg[j] * Ninv + 1e-8;

  double A[3][3];
#pragma unroll
  for (int i = 0; i < 3; ++i)
#pragma unroll
    for (int j = 0; j < 3; ++j)
      A[i][j] = K[0][i] * K[0][j] + K[1][i] * K[1][j] + K[2][i] * K[2][j];

  double V[3][3] = {{1, 0, 0}, {0, 1, 0}, {0, 0, 1}};
  for (int sweep = 0; sweep < 30; ++sweep) {
    const double off = A[0][1] * A[0][1] + A[0][2] * A[0][2] + A[1][2] * A[1][2];
    const double nrm = A[0][0] + A[1][1] + A[2][2];
    if (off <= 1e-30 * nrm * nrm) break;
    for (int pq = 0; pq < 3; ++pq) {
      const int p = (pq == 2) ? 1 : 0;
      const int q = (pq == 0) ? 1 : 2;
      const double apq = A[p][q];
      if (apq == 0.0) continue;
      const double theta = (A[q][q] - A[p][p]) / (2.0 * apq);
      const double tt =
          ((theta >= 0.0) ? 1.0 : -1.0) / (fabs(theta) + sqrt(theta * theta + 1.0));
      const double cc = 1.0 / sqrt(tt * tt + 1.0);
      const double sn = tt * cc;
      const double app = A[p][p], aqq = A[q][q];
      A[p][p] = app - tt * apq;
      A[q][q] = aqq + tt * apq;
      A[p][q] = 0.0; A[q][p] = 0.0;
      const int r = 3 - p - q;
      const double arp = A[r][p], arq = A[r][q];
      A[r][p] = cc * arp - sn * arq; A[p][r] = A[r][p];
      A[r][q] = sn * arp + cc * arq; A[q][r] = A[r][q];
#pragma unroll
      for (int k = 0; k < 3; ++k) {
        const double vkp = V[k][p], vkq = V[k][q];
        V[k][p] = cc * vkp - sn * vkq;
        V[k][q] = sn * vkp + cc * vkq;
      }
    }
  }

  double w[3] = {A[0][0], A[1][1], A[2][2]};
  int i0 = 0, i1 = 1, i2 = 2, tmp;
  if (w[i0] < w[i1]) { tmp = i0; i0 = i1; i1 = tmp; }
  if (w[i0] < w[i2]) { tmp = i0; i0 = i2; i2 = tmp; }
  if (w[i1] < w[i2]) { tmp = i1; i1 = i2; i2 = tmp; }
  const double sv0 = sqrt(fmax(w[i0], 0.0));
  const double sv1 = sqrt(fmax(w[i1], 0.0));
  const double sv2 = sqrt(fmax(w[i2], 0.0));

  const double detK =
      K[0][0] * (K[1][1] * K[2][2] - K[1][2] * K[2][1]) -
      K[0][1] * (K[1][0] * K[2][2] - K[1][2] * K[2][0]) +
      K[0][2] * (K[1][0] * K[2][1] - K[1][1] * K[2][0]);
  const double sgn = (detK > 0.0) ? 1.0 : ((detK < 0.0) ? -1.0 : 0.0);

  const double floor0 = sv0 * 1e-12 + 1e-300;
  const double z0 = 1.0 / fmax(sv0, floor0);
  const double z1 = 1.0 / fmax(sv1, floor0);
  const double z2 = sgn / fmax(sv2, floor0);

  double W[3][3];
#pragma unroll
  for (int a = 0; a < 3; ++a)
#pragma unroll
    for (int c = 0; c < 3; ++c)
      W[a][c] = V[a][i0] * V[c][i0] * z0 + V[a][i1] * V[c][i1] * z1 +
                V[a][i2] * V[c][i2] * z2;

  double R[3][3];
#pragma unroll
  for (int a = 0; a < 3; ++a)
#pragma unroll
    for (int c = 0; c < 3; ++c)
      R[a][c] = W[a][0] * K[c][0] + W[a][1] * K[c][1] + W[a][2] * K[c][2];

  const double trace = sv0 + sv1 + sgn * sv2;
  const double scale = trace / var1;

  float* pr = params + b * 12;
#pragma unroll
  for (int a = 0; a < 3; ++a) {
#pragma unroll
    for (int c = 0; c < 3; ++c) pr[3 * a + c] = (float)(scale * R[a][c]);
    pr[9 + a] = (float)(mu2[a] - scale * (R[a][0] * mu1[0] + R[a][1] * mu1[1] +
                                          R[a][2] * mu1[2]));
  }
}

// ---------------------------------------------------------------------------
// Kernel 3: apply |M p + t - g| per point, LDS-staged.
// grid = (NTILES, BATCH). Coalesced global->LDS stage for pred & gt,
// per-group compute writes results in-place into the pred LDS tile,
// then a coalesced LDS->global store. No 48B-stride global traffic.
// ---------------------------------------------------------------------------
__device__ __forceinline__ void xform(const float* m, float p0, float p1,
                                      float p2, float g0, float g1, float g2,
                                      float& o0, float& o1, float& o2) {
  o0 = fabsf(m[0] * p0 + m[1] * p1 + m[2] * p2 + m[9] - g0);
  o1 = fabsf(m[3] * p0 + m[4] * p1 + m[5] * p2 + m[10] - g1);
  o2 = fabsf(m[6] * p0 + m[7] * p1 + m[8] * p2 + m[11] - g2);
}

__global__ __launch_bounds__(256) void apply_kernel(
    const float* __restrict__ pred, const float* __restrict__ gt,
    const float* __restrict__ params, float* __restrict__ out) {
  const int b = blockIdx.y;
  const int tile = blockIdx.x;
  float m[12];
#pragma unroll
  for (int i = 0; i < 12; ++i) m[i] = params[b * 12 + i];  // uniform -> s_load

  const size_t ofs0 = (size_t)b * FLOATS_PER_BATCH;
  const int skip = (b & 1) ? 2 : 0;
  const size_t ofs = ofs0 + (size_t)skip * 3;
  const float4* __restrict__ P = (const float4*)(pred + ofs);
  const float4* __restrict__ G = (const float4*)(gt + ofs);
  float4* __restrict__ O = (float4*)(out + ofs);

  __shared__ float4 LP[TILE_F4];
  __shared__ float4 LG[TILE_F4];

  const int t = (int)threadIdx.x;
  const int base = tile * TILE_F4;
  const int nf4 = (base + TILE_F4 <= TOTAL_F4) ? TILE_F4 : (TOTAL_F4 - base);

#pragma unroll
  for (int k = 0; k < 3; ++k) {
    const int idx = t + 256 * k;
    if (idx < nf4) {
      LP[idx] = P[base + idx];
      LG[idx] = G[base + idx];
    }
  }
  __syncthreads();

  const int ngr = nf4 / 3;
  if (t < ngr) {
    const float4 a0 = LP[3 * t], a1 = LP[3 * t + 1], a2 = LP[3 * t + 2];
    const float4 c0 = LG[3 * t], c1 = LG[3 * t + 1], c2 = LG[3 * t + 2];
    float4 r0, r1, r2;
    xform(m, a0.x, a0.y, a0.z, c0.x, c0.y, c0.z, r0.x, r0.y, r0.z);
    xform(m, a0.w, a1.x, a1.y, c0.w, c1.x, c1.y, r0.w, r1.x, r1.y);
    xform(m, a1.z, a1.w, a2.x, c1.z, c1.w, c2.x, r1.z, r1.w, r2.x);
    xform(m, a2.y, a2.z, a2.w, c2.y, c2.z, c2.w, r2.y, r2.z, r2.w);
    LP[3 * t] = r0; LP[3 * t + 1] = r1; LP[3 * t + 2] = r2;  // in-place
  }
  __syncthreads();

#pragma unroll
  for (int k = 0; k < 3; ++k) {
    const int idx = t + 256 * k;
    if (idx < nf4) O[base + idx] = LP[idx];
  }

  // 2 leftover scalar points per batch
  if (tile == 0 && t < 2) {
    const int n = skip ? t : (NPTS - 2 + t);
    const float* pp = pred + ofs0 + 3 * n;
    const float* gg = gt + ofs0 + 3 * n;
    float* oo = out + ofs0 + 3 * n;
    xform(m, pp[0], pp[1], pp[2], gg[0], gg[1], gg[2], oo[0], oo[1], oo[2]);
  }
}

extern "C" void kernel_launch(void* const* d_in, const int* in_sizes, int n_in,
                              void* d_out, int out_size, void* d_ws, size_t ws_size,
                              hipStream_t stream) {
  const float* pred = (const float*)d_in[0];
  const float* gt   = (const float*)d_in[1];
  float* out = (float*)d_out;
  float* partial = (float*)d_ws;                    // BATCH*CHUNKS*16 floats
  float* params  = partial + BATCH * CHUNKS * 16;   // BATCH*12 floats

  hipLaunchKernelGGL(reduce_kernel, dim3(BATCH, CHUNKS), dim3(256), 0, stream,
                     pred, gt, partial);
  hipLaunchKernelGGL(solve_kernel, dim3((BATCH + 63) / 64), dim3(64), 0,
                     stream, partial, params);
  hipLaunchKernelGGL(apply_kernel, dim3(NTILES, BATCH), dim3(256), 0, stream,
                     pred, gt, params, out);
}

// Round 3
// 235.886 us; speedup vs baseline: 1.0568x; 1.0493x over previous
//
#include <hip/hip_runtime.h>
#include <math.h>

#define NPTS 6890
#define BATCH 1024
#define FLOATS_PER_BATCH (NPTS * 3)   // 20670; mod 4 == 2
#define NGROUPS 1722                  // groups of 4 points in the aligned region
#define NT 512                        // threads per block (8 waves)

// ---------------------------------------------------------------------------
// Fully fused kernel: one block per batch.
//   Phase 1: load the whole batch (pred+gt) into REGISTERS (3-4 groups of
//            4 points per thread), accumulating the 16 Procrustes sums.
//   Phase 2: block-reduce sums; lane 0 runs the fp64 solve (no runtime-
//            indexed arrays -> stays in registers); params to LDS.
//   Phase 3: apply |scale*R*p + t - g| from the register-held data, store.
// pred/gt are read from memory exactly ONCE per iteration (was twice),
// cutting per-iteration traffic 414 MB -> 245 MB.
// Batch base b*20670 is 16B-aligned only for even b; odd b skips 2 points
// (6 floats) to realign. Leftover 2 points handled scalar by threads 0/1.
// ---------------------------------------------------------------------------

__device__ __forceinline__ void accum(float* acc, float p0, float p1, float p2,
                                      float g0, float g1, float g2) {
  acc[0] += p0;  acc[1] += p1;  acc[2] += p2;
  acc[3] += g0;  acc[4] += g1;  acc[5] += g2;
  acc[6] += p0 * p0 + p1 * p1 + p2 * p2;
  acc[7]  += p0 * g0;  acc[8]  += p0 * g1;  acc[9]  += p0 * g2;
  acc[10] += p1 * g0;  acc[11] += p1 * g1;  acc[12] += p1 * g2;
  acc[13] += p2 * g0;  acc[14] += p2 * g1;  acc[15] += p2 * g2;
}

__device__ __forceinline__ void accum_group(float* acc,
                                            const float4& a0, const float4& a1,
                                            const float4& a2, const float4& e0,
                                            const float4& e1, const float4& e2) {
  accum(acc, a0.x, a0.y, a0.z, e0.x, e0.y, e0.z);
  accum(acc, a0.w, a1.x, a1.y, e0.w, e1.x, e1.y);
  accum(acc, a1.z, a1.w, a2.x, e1.z, e1.w, e2.x);
  accum(acc, a2.y, a2.z, a2.w, e2.y, e2.z, e2.w);
}

__device__ __forceinline__ void xform(const float* m, float p0, float p1,
                                      float p2, float g0, float g1, float g2,
                                      float& o0, float& o1, float& o2) {
  o0 = fabsf(m[0] * p0 + m[1] * p1 + m[2] * p2 + m[9] - g0);
  o1 = fabsf(m[3] * p0 + m[4] * p1 + m[5] * p2 + m[10] - g1);
  o2 = fabsf(m[6] * p0 + m[7] * p1 + m[8] * p2 + m[11] - g2);
}

__device__ __forceinline__ void apply_group(const float* m,
                                            const float4& a0, const float4& a1,
                                            const float4& a2, const float4& e0,
                                            const float4& e1, const float4& e2,
                                            float4& r0, float4& r1, float4& r2) {
  xform(m, a0.x, a0.y, a0.z, e0.x, e0.y, e0.z, r0.x, r0.y, r0.z);
  xform(m, a0.w, a1.x, a1.y, e0.w, e1.x, e1.y, r0.w, r1.x, r1.y);
  xform(m, a1.z, a1.w, a2.x, e1.z, e1.w, e2.x, r1.z, r1.w, r2.x);
  xform(m, a2.y, a2.z, a2.w, e2.y, e2.z, e2.w, r2.y, r2.z, r2.w);
}

// One Jacobi rotation (p,q) with constant indices (fully register-resident).
#define JROT(p, q, r)                                                         \
  do {                                                                        \
    const double apq = A[p][q];                                               \
    if (apq != 0.0) {                                                         \
      const double theta = (A[q][q] - A[p][p]) / (2.0 * apq);                 \
      const double tt = ((theta >= 0.0) ? 1.0 : -1.0) /                       \
                        (fabs(theta) + sqrt(theta * theta + 1.0));            \
      const double cc = 1.0 / sqrt(tt * tt + 1.0);                            \
      const double sn = tt * cc;                                              \
      const double app = A[p][p], aqq = A[q][q];                              \
      A[p][p] = app - tt * apq;                                               \
      A[q][q] = aqq + tt * apq;                                               \
      A[p][q] = 0.0; A[q][p] = 0.0;                                          \
      const double arp = A[r][p], arq = A[r][q];                              \
      A[r][p] = cc * arp - sn * arq; A[p][r] = A[r][p];                       \
      A[r][q] = sn * arp + cc * arq; A[q][r] = A[r][q];                       \
      _Pragma("unroll")                                                       \
      for (int k = 0; k < 3; ++k) {                                           \
        const double vkp = V[k][p], vkq = V[k][q];                            \
        V[k][p] = cc * vkp - sn * vkq;                                        \
        V[k][q] = sn * vkp + cc * vkq;                                        \
      }                                                                       \
    }                                                                         \
  } while (0)

__global__ __launch_bounds__(NT, 2) void fused_kernel(
    const float* __restrict__ pred, const float* __restrict__ gt,
    float* __restrict__ out) {
  const int b = blockIdx.x;
  const int t = (int)threadIdx.x;
  const size_t ofs0 = (size_t)b * FLOATS_PER_BATCH;
  const int skip = (b & 1) ? 2 : 0;                  // points skipped at head
  const size_t ofs = ofs0 + (size_t)skip * 3;        // 16B-aligned float idx
  const float4* __restrict__ P = (const float4*)(pred + ofs);
  const float4* __restrict__ G = (const float4*)(gt + ofs);
  float4* __restrict__ O = (float4*)(out + ofs);

  __shared__ float red[8][16][17];   // cross-wave partials (+1 pad)
  __shared__ float sums_lds[16];
  __shared__ float pm[12];

  // ---- Phase 1: load whole batch into registers, accumulate 16 sums ----
  float4 rp[4][3], rg[4][3];
  const bool has3 = (t < NGROUPS - 3 * NT);          // t < 186
#pragma unroll
  for (int k = 0; k < 3; ++k) {
    const int g = t + NT * k;                        // always < 1536 <= NGROUPS
    rp[k][0] = P[3 * g]; rp[k][1] = P[3 * g + 1]; rp[k][2] = P[3 * g + 2];
    rg[k][0] = G[3 * g]; rg[k][1] = G[3 * g + 1]; rg[k][2] = G[3 * g + 2];
  }
  if (has3) {
    const int g = t + NT * 3;                        // 1536 + t < 1722
    rp[3][0] = P[3 * g]; rp[3][1] = P[3 * g + 1]; rp[3][2] = P[3 * g + 2];
    rg[3][0] = G[3 * g]; rg[3][1] = G[3 * g + 1]; rg[3][2] = G[3 * g + 2];
  }
  // leftover 2 points per batch (head for odd b, tail for even b)
  float lp0 = 0.f, lp1 = 0.f, lp2 = 0.f, lg0 = 0.f, lg1 = 0.f, lg2 = 0.f;
  const bool hasL = (t < 2);
  if (hasL) {
    const int n = skip ? t : (NPTS - 2 + t);
    const float* pp = pred + ofs0 + 3 * n;
    const float* gg = gt + ofs0 + 3 * n;
    lp0 = pp[0]; lp1 = pp[1]; lp2 = pp[2];
    lg0 = gg[0]; lg1 = gg[1]; lg2 = gg[2];
  }

  float acc[16];
#pragma unroll
  for (int i = 0; i < 16; ++i) acc[i] = 0.f;
#pragma unroll
  for (int k = 0; k < 3; ++k)
    accum_group(acc, rp[k][0], rp[k][1], rp[k][2], rg[k][0], rg[k][1], rg[k][2]);
  if (has3)
    accum_group(acc, rp[3][0], rp[3][1], rp[3][2], rg[3][0], rg[3][1], rg[3][2]);
  if (hasL) accum(acc, lp0, lp1, lp2, lg0, lg1, lg2);

  // ---- Phase 2: block reduction + single-lane fp64 solve ----
#pragma unroll
  for (int i = 0; i < 16; ++i) {
    acc[i] += __shfl_xor(acc[i], 16, 64);
    acc[i] += __shfl_xor(acc[i], 32, 64);
  }
  const int wave = t >> 6;
  const int lane = t & 63;
  if (lane < 16) {
#pragma unroll
    for (int i = 0; i < 16; ++i) red[wave][lane][i] = acc[i];
  }
  __syncthreads();
  if (t < 16) {
    float s = 0.f;
#pragma unroll
    for (int w = 0; w < 8; ++w)
#pragma unroll
      for (int r = 0; r < 16; ++r) s += red[w][r][t];
    sums_lds[t] = s;
  }
  __syncthreads();

  if (t == 0) {
    double s[16];
#pragma unroll
    for (int i = 0; i < 16; ++i) s[i] = (double)sums_lds[i];
    const double Ninv = 1.0 / (double)NPTS;
    double sp[3] = {s[0], s[1], s[2]};
    double sg[3] = {s[3], s[4], s[5]};
    double mu1[3], mu2[3];
#pragma unroll
    for (int i = 0; i < 3; ++i) { mu1[i] = sp[i] * Ninv; mu2[i] = sg[i] * Ninv; }
    const double var1 =
        s[6] - (sp[0] * sp[0] + sp[1] * sp[1] + sp[2] * sp[2]) * Ninv;

    double K[3][3];
#pragma unroll
    for (int i = 0; i < 3; ++i)
#pragma unroll
      for (int j = 0; j < 3; ++j)
        K[i][j] = s[7 + 3 * i + j] - sp[i] * sg[j] * Ninv + 1e-8;

    double A[3][3];
#pragma unroll
    for (int i = 0; i < 3; ++i)
#pragma unroll
      for (int j = 0; j < 3; ++j)
        A[i][j] = K[0][i] * K[0][j] + K[1][i] * K[1][j] + K[2][i] * K[2][j];

    double V[3][3] = {{1, 0, 0}, {0, 1, 0}, {0, 0, 1}};
    for (int sweep = 0; sweep < 30; ++sweep) {
      const double off =
          A[0][1] * A[0][1] + A[0][2] * A[0][2] + A[1][2] * A[1][2];
      const double nrm = A[0][0] + A[1][1] + A[2][2];
      if (off <= 1e-30 * nrm * nrm) break;
      JROT(0, 1, 2);
      JROT(0, 2, 1);
      JROT(1, 2, 0);
    }

    // sort eigenvalues descending, carrying V columns (constant indices only)
    double wv[3] = {A[0][0], A[1][1], A[2][2]};
    if (wv[0] < wv[1]) {
      double tw = wv[0]; wv[0] = wv[1]; wv[1] = tw;
#pragma unroll
      for (int k = 0; k < 3; ++k) {
        double tv = V[k][0]; V[k][0] = V[k][1]; V[k][1] = tv;
      }
    }
    if (wv[0] < wv[2]) {
      double tw = wv[0]; wv[0] = wv[2]; wv[2] = tw;
#pragma unroll
      for (int k = 0; k < 3; ++k) {
        double tv = V[k][0]; V[k][0] = V[k][2]; V[k][2] = tv;
      }
    }
    if (wv[1] < wv[2]) {
      double tw = wv[1]; wv[1] = wv[2]; wv[2] = tw;
#pragma unroll
      for (int k = 0; k < 3; ++k) {
        double tv = V[k][1]; V[k][1] = V[k][2]; V[k][2] = tv;
      }
    }
    const double sv0 = sqrt(fmax(wv[0], 0.0));
    const double sv1 = sqrt(fmax(wv[1], 0.0));
    const double sv2 = sqrt(fmax(wv[2], 0.0));

    const double detK =
        K[0][0] * (K[1][1] * K[2][2] - K[1][2] * K[2][1]) -
        K[0][1] * (K[1][0] * K[2][2] - K[1][2] * K[2][0]) +
        K[0][2] * (K[1][0] * K[2][1] - K[1][1] * K[2][0]);
    const double sgn = (detK > 0.0) ? 1.0 : ((detK < 0.0) ? -1.0 : 0.0);

    const double floor0 = sv0 * 1e-12 + 1e-300;
    const double z0 = 1.0 / fmax(sv0, floor0);
    const double z1 = 1.0 / fmax(sv1, floor0);
    const double z2 = sgn / fmax(sv2, floor0);

    double W[3][3];
#pragma unroll
    for (int a = 0; a < 3; ++a)
#pragma unroll
      for (int c = 0; c < 3; ++c)
        W[a][c] = V[a][0] * V[c][0] * z0 + V[a][1] * V[c][1] * z1 +
                  V[a][2] * V[c][2] * z2;

    double R[3][3];
#pragma unroll
    for (int a = 0; a < 3; ++a)
#pragma unroll
      for (int c = 0; c < 3; ++c)
        R[a][c] = W[a][0] * K[c][0] + W[a][1] * K[c][1] + W[a][2] * K[c][2];

    const double trace = sv0 + sv1 + sgn * sv2;
    const double scale = trace / var1;

#pragma unroll
    for (int a = 0; a < 3; ++a) {
#pragma unroll
      for (int c = 0; c < 3; ++c) pm[3 * a + c] = (float)(scale * R[a][c]);
      pm[9 + a] = (float)(mu2[a] - scale * (R[a][0] * mu1[0] +
                                            R[a][1] * mu1[1] +
                                            R[a][2] * mu1[2]));
    }
  }
  __syncthreads();

  // ---- Phase 3: apply from register-held data, store ----
  float m[12];
#pragma unroll
  for (int i = 0; i < 12; ++i) m[i] = pm[i];

#pragma unroll
  for (int k = 0; k < 3; ++k) {
    const int g = t + NT * k;
    float4 r0, r1, r2;
    apply_group(m, rp[k][0], rp[k][1], rp[k][2], rg[k][0], rg[k][1], rg[k][2],
                r0, r1, r2);
    O[3 * g] = r0; O[3 * g + 1] = r1; O[3 * g + 2] = r2;
  }
  if (has3) {
    const int g = t + NT * 3;
    float4 r0, r1, r2;
    apply_group(m, rp[3][0], rp[3][1], rp[3][2], rg[3][0], rg[3][1], rg[3][2],
                r0, r1, r2);
    O[3 * g] = r0; O[3 * g + 1] = r1; O[3 * g + 2] = r2;
  }
  if (hasL) {
    const int n = skip ? t : (NPTS - 2 + t);
    float* oo = out + ofs0 + 3 * n;
    xform(m, lp0, lp1, lp2, lg0, lg1, lg2, oo[0], oo[1], oo[2]);
  }
}

extern "C" void kernel_launch(void* const* d_in, const int* in_sizes, int n_in,
                              void* d_out, int out_size, void* d_ws, size_t ws_size,
                              hipStream_t stream) {
  const float* pred = (const float*)d_in[0];
  const float* gt   = (const float*)d_in[1];
  float* out = (float*)d_out;
  hipLaunchKernelGGL(fused_kernel, dim3(BATCH), dim3(NT), 0, stream,
                     pred, gt, out);
}